// Round 1
// baseline (177.453 us; speedup 1.0000x reference)
//
#include <hip/hip_runtime.h>

// Problem: B=512 rows of F=51200 fp32 features.
// Identity: with MARGIN=1.0, relu(1-sim)==1-sim for all pairs (Cauchy-Schwarz:
// sim<=1), so loss = 1 - (||g||^2 - B)/(B*(B-1)) with g = sum_b f_b/max(||f_b||,eps).
// Labels are mathematically irrelevant. Two streaming passes instead of a GEMM.

#define BROWS 512
#define FDIM  51200
#define F4    (FDIM / 4)      // 12800 float4 per row
#define RCH   8               // row chunks for partial column sums
#define RPC   (BROWS / RCH)   // 64 rows per chunk
#define CBLK  (F4 / 256)      // 50 column blocks

__device__ __forceinline__ float block_reduce_sum_256(float v) {
    // wave-64 shuffle reduce
    #pragma unroll
    for (int off = 32; off > 0; off >>= 1)
        v += __shfl_down(v, off, 64);
    __shared__ float red[4];
    const int lane = threadIdx.x & 63;
    const int wid  = threadIdx.x >> 6;
    if (lane == 0) red[wid] = v;
    __syncthreads();
    if (wid == 0) {
        v = (lane < 4) ? red[lane] : 0.0f;
        v += __shfl_down(v, 2, 64);
        v += __shfl_down(v, 1, 64);
    }
    return v; // valid in thread 0
}

// Pass 1: per-row inverse norms. 512 blocks x 256 threads, float4 coalesced.
__global__ __launch_bounds__(256) void k_norms(const float* __restrict__ f,
                                               float* __restrict__ invn) {
    const int b = blockIdx.x;
    const float4* row = (const float4*)(f + (size_t)b * FDIM);
    float s = 0.0f;
    for (int i = threadIdx.x; i < F4; i += 256) {
        float4 v = row[i];
        s = fmaf(v.x, v.x, s);
        s = fmaf(v.y, v.y, s);
        s = fmaf(v.z, v.z, s);
        s = fmaf(v.w, v.w, s);
    }
    s = block_reduce_sum_256(s);
    if (threadIdx.x == 0) invn[b] = 1.0f / fmaxf(sqrtf(s), 1e-8f);
}

// Pass 2: partial weighted column sums. grid (50, 8) x 256 threads.
// Block (cx, ry): float4-column k4 = cx*256+tid, rows [ry*64, ry*64+64).
__global__ __launch_bounds__(256) void k_wsum(const float* __restrict__ f,
                                              const float* __restrict__ invn,
                                              float* __restrict__ part) {
    const int k4 = blockIdx.x * 256 + threadIdx.x;
    const int r0 = blockIdx.y * RPC;
    const float4* base = (const float4*)f;
    float4 acc = make_float4(0.f, 0.f, 0.f, 0.f);
    #pragma unroll 4
    for (int b = r0; b < r0 + RPC; ++b) {
        const float w = invn[b];              // wave-uniform -> scalar load
        float4 v = base[(size_t)b * F4 + k4]; // coalesced 16B/lane
        acc.x = fmaf(w, v.x, acc.x);
        acc.y = fmaf(w, v.y, acc.y);
        acc.z = fmaf(w, v.z, acc.z);
        acc.w = fmaf(w, v.w, acc.w);
    }
    ((float4*)part)[(size_t)blockIdx.y * F4 + k4] = acc;
}

// Pass 3: g[k] = sum of partials; accumulate ||g||^2 per block. 50 blocks.
__global__ __launch_bounds__(256) void k_sq(const float* __restrict__ part,
                                            float* __restrict__ bsum) {
    const int k4 = blockIdx.x * 256 + threadIdx.x;
    const float4* p = (const float4*)part;
    float4 s = make_float4(0.f, 0.f, 0.f, 0.f);
    #pragma unroll
    for (int r = 0; r < RCH; ++r) {
        float4 v = p[(size_t)r * F4 + k4];
        s.x += v.x; s.y += v.y; s.z += v.z; s.w += v.w;
    }
    float d = s.x * s.x + s.y * s.y + s.z * s.z + s.w * s.w;
    d = block_reduce_sum_256(d);
    if (threadIdx.x == 0) bsum[blockIdx.x] = d;
}

// Pass 4: finalize scalar loss.
__global__ void k_final(const float* __restrict__ bsum, float* __restrict__ out) {
    if (threadIdx.x == 0 && blockIdx.x == 0) {
        float S = 0.0f;
        for (int i = 0; i < CBLK; ++i) S += bsum[i];
        // sum_offdiag(sim) = ||g||^2 - B  (diagonal sims are exactly 1)
        const float denom = (float)BROWS * (float)(BROWS - 1);
        out[0] = 1.0f - (S - (float)BROWS) / denom;
    }
}

extern "C" void kernel_launch(void* const* d_in, const int* in_sizes, int n_in,
                              void* d_out, int out_size, void* d_ws, size_t ws_size,
                              hipStream_t stream) {
    const float* f = (const float*)d_in[0];
    // d_in[1] (labels) is mathematically irrelevant at MARGIN=1.0 — unused.
    float* ws   = (float*)d_ws;
    float* invn = ws;              // 512 floats
    float* bsum = ws + 512;        // 50 floats
    float* part = ws + 1024;       // 8 * 51200 floats = 1.6 MB
    float* out  = (float*)d_out;

    k_norms<<<BROWS, 256, 0, stream>>>(f, invn);
    k_wsum<<<dim3(CBLK, RCH), 256, 0, stream>>>(f, invn, part);
    k_sq<<<CBLK, 256, 0, stream>>>(part, bsum);
    k_final<<<1, 64, 0, stream>>>(bsum, out);
}

// Round 2
// 174.581 us; speedup vs baseline: 1.0164x; 1.0164x over previous
//
#include <hip/hip_runtime.h>

// Problem: B=512 rows of F=51200 fp32 features.
// Identity: with MARGIN=1.0, relu(1-sim)==1-sim for all pairs (Cauchy-Schwarz:
// sim<=1), so loss = 1 - (||g||^2 - B)/(B*(B-1)) with g = sum_b f_b/max(||f_b||,eps).
// Labels are mathematically irrelevant. Two streaming passes instead of a GEMM.
//
// R2: occupancy restructure. Pass1 = 1024 blocks (half-row each, 16 waves/CU).
// Pass2 = 1600 blocks (16-row x 1024-col tiles, ~25 waves/CU), derives invn
// from sqpart in-block (kills the separate finalize dispatch).

#define BROWS 512
#define FDIM  51200
#define F4    (FDIM / 4)       // 12800 float4 per row
#define HALF4 (F4 / 2)         // 6400 float4 per half-row
#define RCH   32               // row chunks in pass 2
#define RPC   (BROWS / RCH)    // 16 rows per chunk
#define CBLK  (F4 / 256)       // 50 column blocks

__device__ __forceinline__ float block_reduce_sum_256(float v) {
    #pragma unroll
    for (int off = 32; off > 0; off >>= 1)
        v += __shfl_down(v, off, 64);
    __shared__ float red[4];
    const int lane = threadIdx.x & 63;
    const int wid  = threadIdx.x >> 6;
    if (lane == 0) red[wid] = v;
    __syncthreads();
    if (wid == 0) {
        v = (lane < 4) ? red[lane] : 0.0f;
        v += __shfl_down(v, 2, 64);
        v += __shfl_down(v, 1, 64);
    }
    return v; // valid in thread 0
}

// Pass 1: half-row sum of squares. 1024 blocks x 256 threads (16 waves/CU).
// Each thread: 25 independent float4 loads, 4 separate component chains.
__global__ __launch_bounds__(256) void k_sq_partial(const float* __restrict__ f,
                                                    float* __restrict__ sqpart) {
    const int row  = blockIdx.x >> 1;
    const int half = blockIdx.x & 1;
    const float4* seg = (const float4*)(f + (size_t)row * FDIM) + half * HALF4;
    float sx = 0.f, sy = 0.f, sz = 0.f, sw = 0.f;
    #pragma unroll 5
    for (int j = 0; j < 25; ++j) {
        float4 v = seg[threadIdx.x + j * 256];
        sx = fmaf(v.x, v.x, sx);
        sy = fmaf(v.y, v.y, sy);
        sz = fmaf(v.z, v.z, sz);
        sw = fmaf(v.w, v.w, sw);
    }
    float s = block_reduce_sum_256((sx + sy) + (sz + sw));
    if (threadIdx.x == 0) sqpart[blockIdx.x] = s;
}

// Pass 2: partial weighted column sums. grid (50, 32) x 256 threads.
// Block (cx, ry): float4-col k4 = cx*256+tid, rows [ry*16, ry*16+16).
// invn derived from sqpart per block (64B LDS).
__global__ __launch_bounds__(256) void k_wsum(const float* __restrict__ f,
                                              const float* __restrict__ sqpart,
                                              float* __restrict__ part) {
    __shared__ float winv[RPC];
    const int r0 = blockIdx.y * RPC;
    if (threadIdx.x < RPC) {
        const int b = r0 + threadIdx.x;
        const float s = sqpart[2 * b] + sqpart[2 * b + 1];
        winv[threadIdx.x] = 1.0f / fmaxf(sqrtf(s), 1e-8f);
    }
    __syncthreads();
    const int k4 = blockIdx.x * 256 + threadIdx.x;
    const float4* base = (const float4*)f;
    float4 acc = make_float4(0.f, 0.f, 0.f, 0.f);
    #pragma unroll 8
    for (int j = 0; j < RPC; ++j) {
        const float w = winv[j];                        // wave-uniform broadcast
        float4 v = base[(size_t)(r0 + j) * F4 + k4];    // coalesced 16B/lane
        acc.x = fmaf(w, v.x, acc.x);
        acc.y = fmaf(w, v.y, acc.y);
        acc.z = fmaf(w, v.z, acc.z);
        acc.w = fmaf(w, v.w, acc.w);
    }
    ((float4*)part)[(size_t)blockIdx.y * F4 + k4] = acc;
}

// Pass 3: g[k] = sum of 32 partials; accumulate ||g||^2 per block. 50 blocks.
__global__ __launch_bounds__(256) void k_sq(const float* __restrict__ part,
                                            float* __restrict__ bsum) {
    const int k4 = blockIdx.x * 256 + threadIdx.x;
    const float4* p = (const float4*)part;
    float4 s = make_float4(0.f, 0.f, 0.f, 0.f);
    #pragma unroll 8
    for (int r = 0; r < RCH; ++r) {
        float4 v = p[(size_t)r * F4 + k4];
        s.x += v.x; s.y += v.y; s.z += v.z; s.w += v.w;
    }
    float d = s.x * s.x + s.y * s.y + s.z * s.z + s.w * s.w;
    d = block_reduce_sum_256(d);
    if (threadIdx.x == 0) bsum[blockIdx.x] = d;
}

// Pass 4: finalize scalar loss (wave-parallel partial load).
__global__ void k_final(const float* __restrict__ bsum, float* __restrict__ out) {
    const int t = threadIdx.x;
    float v = (t < CBLK) ? bsum[t] : 0.0f;
    #pragma unroll
    for (int off = 32; off > 0; off >>= 1)
        v += __shfl_down(v, off, 64);
    if (t == 0) {
        const float denom = (float)BROWS * (float)(BROWS - 1);
        out[0] = 1.0f - (v - (float)BROWS) / denom;   // diag sims are exactly 1
    }
}

extern "C" void kernel_launch(void* const* d_in, const int* in_sizes, int n_in,
                              void* d_out, int out_size, void* d_ws, size_t ws_size,
                              hipStream_t stream) {
    const float* f = (const float*)d_in[0];
    // d_in[1] (labels) is mathematically irrelevant at MARGIN=1.0 — unused.
    float* ws     = (float*)d_ws;
    float* sqpart = ws;            // 1024 floats
    float* bsum   = ws + 1024;     // 50 floats
    float* part   = ws + 2048;     // 32 * 12800 float4 = 6.55 MB (16B-aligned)
    float* out    = (float*)d_out;

    k_sq_partial<<<2 * BROWS, 256, 0, stream>>>(f, sqpart);
    k_wsum<<<dim3(CBLK, RCH), 256, 0, stream>>>(f, sqpart, part);
    k_sq<<<CBLK, 256, 0, stream>>>(part, bsum);
    k_final<<<1, 64, 0, stream>>>(bsum, out);
}